// Round 1
// baseline (1123.876 us; speedup 1.0000x reference)
//
#include <hip/hip_runtime.h>
#include <hip/hip_bf16.h>

#define M_DIM 16384
#define N_DIM 4096
#define K_DIM 4096
#define FP8_MAX 448.0f

#define BM 128
#define BN 128
#define BK 64
#define NKT (K_DIM / BK)

typedef float f32x4 __attribute__((ext_vector_type(4)));
typedef long long i64;

// ---------------- init ----------------
__global__ void init_amax_kernel(unsigned* amax) {
    if (threadIdx.x < 2) amax[threadIdx.x] = 0u;
}

// ---------------- amax reduction ----------------
__global__ void amax_kernel(const float* __restrict__ p, long n4,
                            unsigned* __restrict__ out) {
    float m = 0.f;
    const float4* p4 = (const float4*)p;
    for (long i = (long)blockIdx.x * blockDim.x + threadIdx.x; i < n4;
         i += (long)gridDim.x * blockDim.x) {
        float4 v = p4[i];
        m = fmaxf(m, fmaxf(fmaxf(fabsf(v.x), fabsf(v.y)),
                           fmaxf(fabsf(v.z), fabsf(v.w))));
    }
#pragma unroll
    for (int off = 32; off > 0; off >>= 1)
        m = fmaxf(m, __shfl_down(m, off));
    __shared__ float smax[4];
    int lane = threadIdx.x & 63, wid = threadIdx.x >> 6;
    if (lane == 0) smax[wid] = m;
    __syncthreads();
    if (threadIdx.x == 0) {
        float bm = fmaxf(fmaxf(smax[0], smax[1]), fmaxf(smax[2], smax[3]));
        atomicMax(out, __float_as_uint(bm));  // positive floats: bit order == value order
    }
}

// ---------------- quantize x (M,K) fp32 -> fp8 ----------------
__global__ void quant_x_kernel(const float* __restrict__ x,
                               unsigned char* __restrict__ q,
                               const unsigned* __restrict__ amax) {
    float a = __uint_as_float(amax[0]);
    float scale = FP8_MAX / fmaxf(a, 1e-12f);
    const long n8 = (long)M_DIM * K_DIM / 8;
    const float4* x4 = (const float4*)x;
    uint2* q8 = (uint2*)q;
    for (long i = (long)blockIdx.x * blockDim.x + threadIdx.x; i < n8;
         i += (long)gridDim.x * blockDim.x) {
        float4 v0 = x4[2 * i];
        float4 v1 = x4[2 * i + 1];
        float c0 = fminf(fmaxf(v0.x * scale, -FP8_MAX), FP8_MAX);
        float c1 = fminf(fmaxf(v0.y * scale, -FP8_MAX), FP8_MAX);
        float c2 = fminf(fmaxf(v0.z * scale, -FP8_MAX), FP8_MAX);
        float c3 = fminf(fmaxf(v0.w * scale, -FP8_MAX), FP8_MAX);
        float c4 = fminf(fmaxf(v1.x * scale, -FP8_MAX), FP8_MAX);
        float c5 = fminf(fmaxf(v1.y * scale, -FP8_MAX), FP8_MAX);
        float c6 = fminf(fmaxf(v1.z * scale, -FP8_MAX), FP8_MAX);
        float c7 = fminf(fmaxf(v1.w * scale, -FP8_MAX), FP8_MAX);
        int lo = 0, hi = 0;
        lo = __builtin_amdgcn_cvt_pk_fp8_f32(c0, c1, lo, false);
        lo = __builtin_amdgcn_cvt_pk_fp8_f32(c2, c3, lo, true);
        hi = __builtin_amdgcn_cvt_pk_fp8_f32(c4, c5, hi, false);
        hi = __builtin_amdgcn_cvt_pk_fp8_f32(c6, c7, hi, true);
        uint2 o;
        o.x = (unsigned)lo;
        o.y = (unsigned)hi;
        q8[i] = o;
    }
}

// ------------- quantize + transpose weight (K,N) -> qw (N,K) fp8 -------------
__global__ void quant_wt_kernel(const float* __restrict__ w,
                                unsigned char* __restrict__ qw,
                                const unsigned* __restrict__ amax) {
    __shared__ unsigned char tile[64][68];  // pad 68: conflict-free transposed byte stores
    float a = __uint_as_float(amax[1]);
    float scale = FP8_MAX / fmaxf(a, 1e-12f);
    int b = blockIdx.x;
    int bk = b & 63;         // K/64 = 64 tiles
    int bn = b >> 6;         // N/64 = 64 tiles
    int k0 = bk * 64, n0 = bn * 64;
    int col = threadIdx.x & 63;   // n within tile
    int g = threadIdx.x >> 6;     // 0..3
#pragma unroll
    for (int r = 0; r < 16; ++r) {
        int kr = g * 16 + r;
        float v = w[(long)(k0 + kr) * N_DIM + n0 + col];
        v = fminf(fmaxf(v * scale, -FP8_MAX), FP8_MAX);
        int p = __builtin_amdgcn_cvt_pk_fp8_f32(v, v, 0, false);
        tile[col][kr] = (unsigned char)(p & 0xff);
    }
    __syncthreads();
    int n = threadIdx.x >> 2;
    int ch = threadIdx.x & 3;
    const unsigned* tp = (const unsigned*)&tile[n][ch * 16];
    uint4 o;
    o.x = tp[0]; o.y = tp[1]; o.z = tp[2]; o.w = tp[3];
    *(uint4*)&qw[(long)(n0 + n) * K_DIM + k0 + ch * 16] = o;
}

// ---------------- fp8 GEMM: out(M,N) = qa(M,K) * qw(N,K)^T * s ----------------
__device__ __forceinline__ void stage_tile(const unsigned char* __restrict__ Aseg,
                                           const unsigned char* __restrict__ Bseg,
                                           unsigned char* Albuf, unsigned char* Blbuf,
                                           int tid, int k0) {
#pragma unroll
    for (int r = 0; r < 2; ++r) {
        int chunk = r * 256 + tid;
        int row = chunk >> 2;
        int koff = (chunk & 3) << 4;
        __builtin_amdgcn_global_load_lds(
            (const __attribute__((address_space(1))) void*)(Aseg + (long)row * K_DIM + k0 + koff),
            (__attribute__((address_space(3))) void*)(Albuf + chunk * 16), 16, 0, 0);
        __builtin_amdgcn_global_load_lds(
            (const __attribute__((address_space(1))) void*)(Bseg + (long)row * K_DIM + k0 + koff),
            (__attribute__((address_space(3))) void*)(Blbuf + chunk * 16), 16, 0, 0);
    }
}

__global__ __launch_bounds__(256) void gemm_fp8_kernel(
    const unsigned char* __restrict__ qa, const unsigned char* __restrict__ qw,
    float* __restrict__ out, const unsigned* __restrict__ amax) {
    __shared__ unsigned char Alds[2][BM * BK];  // 8KB x2
    __shared__ unsigned char Blds[2][BN * BK];  // 8KB x2

    // XCD-bijective swizzle (nwg = 4096, divisible by 8)
    int b = blockIdx.x;
    int swz = (b & 7) * ((M_DIM / BM) * (N_DIM / BN) / 8) + (b >> 3);
    int bm = swz >> 5;          // N_DIM/BN = 32
    int bn = swz & 31;
    long m0 = (long)bm * BM;
    long n0 = (long)bn * BN;

    int tid = threadIdx.x;
    int lane = tid & 63;
    int w = tid >> 6;
    int wm = w >> 1, wn = w & 1;   // 2x2 wave grid, 64x64 out per wave

    f32x4 acc[4][4];
#pragma unroll
    for (int i = 0; i < 4; ++i)
#pragma unroll
        for (int j = 0; j < 4; ++j) acc[i][j] = (f32x4)0.f;

    const unsigned char* Aseg = qa + m0 * K_DIM;
    const unsigned char* Bseg = qw + n0 * K_DIM;

    stage_tile(Aseg, Bseg, &Alds[0][0], &Blds[0][0], tid, 0);
    __syncthreads();

    int arow0 = wm * 64 + (lane & 15);
    int brow0 = wn * 64 + (lane & 15);
    int koffl = (lane >> 4) * 8;

    int cur = 0;
    for (int kt = 0; kt < NKT; ++kt) {
        if (kt + 1 < NKT)
            stage_tile(Aseg, Bseg, &Alds[cur ^ 1][0], &Blds[cur ^ 1][0], tid,
                       (kt + 1) * BK);
#pragma unroll
        for (int kk = 0; kk < 2; ++kk) {
            i64 afr[4], bfr[4];
#pragma unroll
            for (int i = 0; i < 4; ++i)
                afr[i] = *(const i64*)&Alds[cur][(arow0 + i * 16) * BK + kk * 32 + koffl];
#pragma unroll
            for (int j = 0; j < 4; ++j)
                bfr[j] = *(const i64*)&Blds[cur][(brow0 + j * 16) * BK + kk * 32 + koffl];
#pragma unroll
            for (int i = 0; i < 4; ++i)
#pragma unroll
                for (int j = 0; j < 4; ++j)
                    acc[i][j] = __builtin_amdgcn_mfma_f32_16x16x32_fp8_fp8(
                        afr[i], bfr[j], acc[i][j], 0, 0, 0);
        }
        __syncthreads();   // drains vmcnt: next buffer staged; all reads of cur done
        cur ^= 1;
    }

    // epilogue: dequant scale = (amax_x/448) * (amax_w/448)
    float ax = fmaxf(__uint_as_float(amax[0]), 1e-12f);
    float aw = fmaxf(__uint_as_float(amax[1]), 1e-12f);
    float s = ax * aw * (1.0f / (FP8_MAX * FP8_MAX));

    long crow0 = m0 + wm * 64 + ((lane >> 4) * 4);
    long ccol0 = n0 + wn * 64 + (lane & 15);
#pragma unroll
    for (int i = 0; i < 4; ++i)
#pragma unroll
        for (int j = 0; j < 4; ++j)
#pragma unroll
            for (int r = 0; r < 4; ++r)
                out[(crow0 + i * 16 + r) * N_DIM + ccol0 + j * 16] = acc[i][j][r] * s;
}

extern "C" void kernel_launch(void* const* d_in, const int* in_sizes, int n_in,
                              void* d_out, int out_size, void* d_ws, size_t ws_size,
                              hipStream_t stream) {
    const float* x = (const float*)d_in[0];       // (8,2048,4096) = (M,K)
    const float* wgt = (const float*)d_in[1];     // (K,N)
    float* out = (float*)d_out;

    // workspace layout
    unsigned* amax = (unsigned*)d_ws;                         // 2 words
    unsigned char* qa = (unsigned char*)d_ws + 256;           // M*K fp8 = 64MB
    unsigned char* qw = qa + (long)M_DIM * K_DIM;             // N*K fp8 = 16MB

    init_amax_kernel<<<1, 64, 0, stream>>>(amax);
    amax_kernel<<<2048, 256, 0, stream>>>(x, (long)M_DIM * K_DIM / 4, amax + 0);
    amax_kernel<<<1024, 256, 0, stream>>>(wgt, (long)K_DIM * N_DIM / 4, amax + 1);
    quant_x_kernel<<<2048, 256, 0, stream>>>(x, qa, amax);
    quant_wt_kernel<<<4096, 256, 0, stream>>>(wgt, qw, amax);

    dim3 grid((M_DIM / BM) * (N_DIM / BN));  // 4096
    gemm_fp8_kernel<<<grid, 256, 0, stream>>>(qa, qw, out, amax);
}

// Round 2
// 736.473 us; speedup vs baseline: 1.5260x; 1.5260x over previous
//
#include <hip/hip_runtime.h>
#include <hip/hip_bf16.h>

#define M_DIM 16384
#define N_DIM 4096
#define K_DIM 4096
#define FP8_MAX 448.0f

#define BM 128
#define BN 128
#define BK 64
#define NKT (K_DIM / BK)

typedef float f32x4 __attribute__((ext_vector_type(4)));
typedef long long i64;
typedef i64 i64x2 __attribute__((ext_vector_type(2)));

// Packed fp8 operand layout (both A and B):
//   [row16-block][k64-block][lane 0..63][16 bytes]
// lane l holds: row = row16*16 + (l&15);
//   bytes 0..7  = k64*64 + (l>>4)*8 + 0..7   (k32 slot 0 MFMA fragment)
//   bytes 8..15 = k64*64 + 32 + (l>>4)*8 + 0..7 (k32 slot 1 fragment)
// => GEMM LDS reads are ds_read_b128 at base + lane*16 (conflict-free),
//    global_load_lds staging is linear, quant kernels bake the permutation.

// ---------------- init ----------------
__global__ void init_amax_kernel(unsigned* amax) {
    if (threadIdx.x < 2) amax[threadIdx.x] = 0u;
}

// ---------------- amax reduction ----------------
__global__ void amax_kernel(const float* __restrict__ p, long n4,
                            unsigned* __restrict__ out) {
    float m = 0.f;
    const float4* p4 = (const float4*)p;
    for (long i = (long)blockIdx.x * blockDim.x + threadIdx.x; i < n4;
         i += (long)gridDim.x * blockDim.x) {
        float4 v = p4[i];
        m = fmaxf(m, fmaxf(fmaxf(fabsf(v.x), fabsf(v.y)),
                           fmaxf(fabsf(v.z), fabsf(v.w))));
    }
#pragma unroll
    for (int off = 32; off > 0; off >>= 1)
        m = fmaxf(m, __shfl_down(m, off));
    __shared__ float smax[4];
    int lane = threadIdx.x & 63, wid = threadIdx.x >> 6;
    if (lane == 0) smax[wid] = m;
    __syncthreads();
    if (threadIdx.x == 0) {
        float bm = fmaxf(fmaxf(smax[0], smax[1]), fmaxf(smax[2], smax[3]));
        atomicMax(out, __float_as_uint(bm));  // positive floats: bit order == value order
    }
}

__device__ __forceinline__ unsigned pack4(float4 v, float s) {
    float a = fminf(fmaxf(v.x * s, -FP8_MAX), FP8_MAX);
    float b = fminf(fmaxf(v.y * s, -FP8_MAX), FP8_MAX);
    float c = fminf(fmaxf(v.z * s, -FP8_MAX), FP8_MAX);
    float d = fminf(fmaxf(v.w * s, -FP8_MAX), FP8_MAX);
    int p = 0;
    p = __builtin_amdgcn_cvt_pk_fp8_f32(a, b, p, false);
    p = __builtin_amdgcn_cvt_pk_fp8_f32(c, d, p, true);
    return (unsigned)p;
}

// ---------------- quantize x (M,K) fp32 -> packed fp8 ----------------
__global__ void quant_x_kernel(const float* __restrict__ x,
                               unsigned char* __restrict__ q,
                               const unsigned* __restrict__ amax) {
    float scale = FP8_MAX / fmaxf(__uint_as_float(amax[0]), 1e-12f);
    int m16 = blockIdx.x;                 // 0..1023 (M/16)
    int t = threadIdx.x;
    int lane = t & 63;
    int g2 = t >> 6;                      // 0..3: k64 sub-block per iteration
    int m = m16 * 16 + (lane & 15);
    int kbl = (lane >> 4) * 8;
    const float* row = x + (long)m * K_DIM;
    unsigned char* outb = q + (long)m16 * (K_DIM / 64) * 1024;
#pragma unroll
    for (int it = 0; it < 16; ++it) {     // K/64 = 64 k64-blocks, 4 per iter
        int k64 = it * 4 + g2;
        int kb = k64 * 64 + kbl;
        float4 v0 = *(const float4*)&row[kb];
        float4 v1 = *(const float4*)&row[kb + 4];
        float4 v2 = *(const float4*)&row[kb + 32];
        float4 v3 = *(const float4*)&row[kb + 36];
        uint4 o;
        o.x = pack4(v0, scale);
        o.y = pack4(v1, scale);
        o.z = pack4(v2, scale);
        o.w = pack4(v3, scale);
        *(uint4*)&outb[(long)k64 * 1024 + lane * 16] = o;
    }
}

// ------- quantize + transpose weight (K,N) -> packed fp8 (N-major) -------
__global__ void quant_wt_kernel(const float* __restrict__ w,
                                unsigned char* __restrict__ qw,
                                const unsigned* __restrict__ amax) {
    __shared__ unsigned tile[64][17];     // [k][n-word], pad 17: conflict-light
    float scale = FP8_MAX / fmaxf(__uint_as_float(amax[1]), 1e-12f);
    int b = blockIdx.x;                   // 4096 = (K/64) * (N/64)
    int bk = b & 63, bn = b >> 6;
    int k0 = bk * 64, n0 = bn * 64;
    int t = threadIdx.x;
    int nw = t & 15, kl = t >> 4;
#pragma unroll
    for (int pass = 0; pass < 4; ++pass) {
        int k = pass * 16 + kl;
        float4 v = *(const float4*)&w[(long)(k0 + k) * N_DIM + n0 + nw * 4];
        tile[k][nw] = pack4(v, scale);
    }
    __syncthreads();
    // emit 256 lanes x 16B (packed fragments, fully coalesced)
    int lane = t & 63;
    int n16l = t >> 6;                    // 0..3
    int nl = n16l * 16 + (lane & 15);
    int kb = (lane >> 4) * 8;
    int word = nl >> 2, sh = (nl & 3) * 8;
    unsigned b0 = 0, b1 = 0, b2 = 0, b3 = 0;
#pragma unroll
    for (int j = 0; j < 4; ++j) b0 |= ((tile[kb + j][word] >> sh) & 0xffu) << (8 * j);
#pragma unroll
    for (int j = 0; j < 4; ++j) b1 |= ((tile[kb + 4 + j][word] >> sh) & 0xffu) << (8 * j);
#pragma unroll
    for (int j = 0; j < 4; ++j) b2 |= ((tile[kb + 32 + j][word] >> sh) & 0xffu) << (8 * j);
#pragma unroll
    for (int j = 0; j < 4; ++j) b3 |= ((tile[kb + 36 + j][word] >> sh) & 0xffu) << (8 * j);
    uint4 o;
    o.x = b0; o.y = b1; o.z = b2; o.w = b3;
    long gn16 = (long)(n0 >> 4) + n16l;
    *(uint4*)&qw[(gn16 * (K_DIM / 64) + bk) * 1024 + lane * 16] = o;
}

// ---------------- fp8 GEMM on packed operands ----------------
__device__ __forceinline__ void stage_tile(const unsigned char* __restrict__ Aseg,
                                           const unsigned char* __restrict__ Bseg,
                                           unsigned char* Al, unsigned char* Bl,
                                           int tid, int kt) {
#pragma unroll
    for (int r = 0; r < 2; ++r) {
        int chunk = r * 256 + tid;        // 0..511
        int f = chunk >> 6;               // row16-local 0..7
        int q = chunk & 63;               // lane slot within fragment-pair
        long goff = ((long)f * (K_DIM / 64) + kt) * 1024 + q * 16;
        __builtin_amdgcn_global_load_lds(
            (const __attribute__((address_space(1))) void*)(Aseg + goff),
            (__attribute__((address_space(3))) void*)(Al + chunk * 16), 16, 0, 0);
        __builtin_amdgcn_global_load_lds(
            (const __attribute__((address_space(1))) void*)(Bseg + goff),
            (__attribute__((address_space(3))) void*)(Bl + chunk * 16), 16, 0, 0);
    }
}

__global__ __launch_bounds__(256) void gemm_fp8_kernel(
    const unsigned char* __restrict__ qa, const unsigned char* __restrict__ qw,
    float* __restrict__ out, const unsigned* __restrict__ amax) {
    __shared__ unsigned char Alds[2][BM * BK];  // 8KB x2
    __shared__ unsigned char Blds[2][BN * BK];  // 8KB x2

    // XCD-bijective swizzle (nwg = 4096, divisible by 8)
    int b = blockIdx.x;
    int swz = (b & 7) * ((M_DIM / BM) * (N_DIM / BN) / 8) + (b >> 3);
    int bm = swz >> 5;          // N_DIM/BN = 32
    int bn = swz & 31;

    int tid = threadIdx.x;
    int lane = tid & 63;
    int w = tid >> 6;
    int wm = w >> 1, wn = w & 1;   // 2x2 wave grid, 64x64 out per wave

    f32x4 acc[4][4];
#pragma unroll
    for (int i = 0; i < 4; ++i)
#pragma unroll
        for (int j = 0; j < 4; ++j) acc[i][j] = (f32x4)0.f;

    const unsigned char* Aseg = qa + (long)(bm * 8) * (K_DIM / 64) * 1024;
    const unsigned char* Bseg = qw + (long)(bn * 8) * (K_DIM / 64) * 1024;

    stage_tile(Aseg, Bseg, &Alds[0][0], &Blds[0][0], tid, 0);
    __syncthreads();

    int abase = wm * 4 * 1024 + lane * 16;   // wave's 4 row16-blocks
    int bbase = wn * 4 * 1024 + lane * 16;

    int cur = 0;
    for (int kt = 0; kt < NKT; ++kt) {
        if (kt + 1 < NKT)
            stage_tile(Aseg, Bseg, &Alds[cur ^ 1][0], &Blds[cur ^ 1][0], tid, kt + 1);
        i64x2 af[4], bf[4];
#pragma unroll
        for (int i = 0; i < 4; ++i)
            af[i] = *(const i64x2*)&Alds[cur][abase + i * 1024];
#pragma unroll
        for (int j = 0; j < 4; ++j)
            bf[j] = *(const i64x2*)&Blds[cur][bbase + j * 1024];
#pragma unroll
        for (int i = 0; i < 4; ++i)
#pragma unroll
            for (int j = 0; j < 4; ++j)
                acc[i][j] = __builtin_amdgcn_mfma_f32_16x16x32_fp8_fp8(
                    af[i][0], bf[j][0], acc[i][j], 0, 0, 0);
#pragma unroll
        for (int i = 0; i < 4; ++i)
#pragma unroll
            for (int j = 0; j < 4; ++j)
                acc[i][j] = __builtin_amdgcn_mfma_f32_16x16x32_fp8_fp8(
                    af[i][1], bf[j][1], acc[i][j], 0, 0, 0);
        __syncthreads();   // drains vmcnt: next buffer staged; all reads of cur done
        cur ^= 1;
    }

    // epilogue: dequant scale = (amax_x/448) * (amax_w/448)
    float ax = fmaxf(__uint_as_float(amax[0]), 1e-12f);
    float aw = fmaxf(__uint_as_float(amax[1]), 1e-12f);
    float s = ax * aw * (1.0f / (FP8_MAX * FP8_MAX));

    long m0 = (long)bm * BM;
    long n0 = (long)bn * BN;
    long crow0 = m0 + wm * 64 + ((lane >> 4) * 4);
    long ccol0 = n0 + wn * 64 + (lane & 15);
#pragma unroll
    for (int i = 0; i < 4; ++i)
#pragma unroll
        for (int j = 0; j < 4; ++j)
#pragma unroll
            for (int r = 0; r < 4; ++r)
                out[(crow0 + i * 16 + r) * N_DIM + ccol0 + j * 16] = acc[i][j][r] * s;
}

extern "C" void kernel_launch(void* const* d_in, const int* in_sizes, int n_in,
                              void* d_out, int out_size, void* d_ws, size_t ws_size,
                              hipStream_t stream) {
    const float* x = (const float*)d_in[0];       // (8,2048,4096) = (M,K)
    const float* wgt = (const float*)d_in[1];     // (K,N)
    float* out = (float*)d_out;

    // workspace layout
    unsigned* amax = (unsigned*)d_ws;                         // 2 words
    unsigned char* qa = (unsigned char*)d_ws + 256;           // M*K fp8 = 64MB packed
    unsigned char* qw = qa + (long)M_DIM * K_DIM;             // N*K fp8 = 16MB packed

    init_amax_kernel<<<1, 64, 0, stream>>>(amax);
    amax_kernel<<<2048, 256, 0, stream>>>(x, (long)M_DIM * K_DIM / 4, amax + 0);
    amax_kernel<<<1024, 256, 0, stream>>>(wgt, (long)K_DIM * N_DIM / 4, amax + 1);
    quant_x_kernel<<<M_DIM / 16, 256, 0, stream>>>(x, qa, amax);
    quant_wt_kernel<<<(K_DIM / 64) * (N_DIM / 64), 256, 0, stream>>>(wgt, qw, amax);

    dim3 grid((M_DIM / BM) * (N_DIM / BN));  // 4096
    gemm_fp8_kernel<<<grid, 256, 0, stream>>>(qa, qw, out, amax);
}

// Round 3
// 689.954 us; speedup vs baseline: 1.6289x; 1.0674x over previous
//
#include <hip/hip_runtime.h>
#include <hip/hip_bf16.h>

#define M_DIM 16384
#define N_DIM 4096
#define K_DIM 4096
#define FP8_MAX 448.0f

#define BM 128
#define BN 128
#define BK 128
#define NKT (K_DIM / BK)   // 32
#define NK128 (K_DIM / 128)

typedef float f32x4 __attribute__((ext_vector_type(4)));
typedef int i32x4 __attribute__((ext_vector_type(4)));
typedef int i32x8 __attribute__((ext_vector_type(8)));

// Packed fp8 operand layout (A and B identical), matched to the
// mfma_scale_f32_16x16x128_f8f6f4 fragment: lane l holds
//   row = row16*16 + (l&15),  k = k128*128 + (l>>4)*32 + {0..31}
// stored as [row16-block][k128-block]{ h=0: lane*16 = k +0..15 ;
//                                      h=1: 1024 + lane*16 = k +16..31 }
// => GEMM LDS reads: 2x ds_read_b128 @ base + lane*16 (conflict-free),
//    staging linear via global_load_lds w=16; quant kernels bake the order.
// Scales: e8m0 = 127 (1.0) everywhere -> bit-identical to plain fp8 GEMM.

// ---------------- init ----------------
__global__ void init_amax_kernel(unsigned* amax) {
    if (threadIdx.x < 2) amax[threadIdx.x] = 0u;
}

// ---------------- amax reduction ----------------
__global__ void amax_kernel(const float* __restrict__ p, long n4,
                            unsigned* __restrict__ out) {
    float m = 0.f;
    const float4* p4 = (const float4*)p;
    for (long i = (long)blockIdx.x * blockDim.x + threadIdx.x; i < n4;
         i += (long)gridDim.x * blockDim.x) {
        float4 v = p4[i];
        m = fmaxf(m, fmaxf(fmaxf(fabsf(v.x), fabsf(v.y)),
                           fmaxf(fabsf(v.z), fabsf(v.w))));
    }
#pragma unroll
    for (int off = 32; off > 0; off >>= 1)
        m = fmaxf(m, __shfl_down(m, off));
    __shared__ float smax[4];
    int lane = threadIdx.x & 63, wid = threadIdx.x >> 6;
    if (lane == 0) smax[wid] = m;
    __syncthreads();
    if (threadIdx.x == 0) {
        float bm = fmaxf(fmaxf(smax[0], smax[1]), fmaxf(smax[2], smax[3]));
        atomicMax(out, __float_as_uint(bm));  // positive floats: bit order == value order
    }
}

__device__ __forceinline__ unsigned pack4(float4 v, float s) {
    float a = fminf(fmaxf(v.x * s, -FP8_MAX), FP8_MAX);
    float b = fminf(fmaxf(v.y * s, -FP8_MAX), FP8_MAX);
    float c = fminf(fmaxf(v.z * s, -FP8_MAX), FP8_MAX);
    float d = fminf(fmaxf(v.w * s, -FP8_MAX), FP8_MAX);
    int p = 0;
    p = __builtin_amdgcn_cvt_pk_fp8_f32(a, b, p, false);
    p = __builtin_amdgcn_cvt_pk_fp8_f32(c, d, p, true);
    return (unsigned)p;
}

// ---------------- quantize x (M,K) fp32 -> packed fp8 ----------------
__global__ void quant_x_kernel(const float* __restrict__ x,
                               unsigned char* __restrict__ q,
                               const unsigned* __restrict__ amax) {
    float scale = FP8_MAX / fmaxf(__uint_as_float(amax[0]), 1e-12f);
    int m16 = blockIdx.x;                 // 0..1023 (M/16)
    int t = threadIdx.x;
    int lane = t & 63;
    int g2 = t >> 6;                      // 0..3: k128 sub-block per iteration
    int m = m16 * 16 + (lane & 15);
    int kbl = (lane >> 4) * 32;
    const float* row = x + (long)m * K_DIM;
    unsigned char* outb = q + (long)m16 * NK128 * 2048;
#pragma unroll
    for (int it = 0; it < 8; ++it) {      // 32 k128-blocks, 4 per iter
        int k128 = it * 4 + g2;
        int kb = k128 * 128 + kbl;
        float4 v0 = *(const float4*)&row[kb];
        float4 v1 = *(const float4*)&row[kb + 4];
        float4 v2 = *(const float4*)&row[kb + 8];
        float4 v3 = *(const float4*)&row[kb + 12];
        float4 v4 = *(const float4*)&row[kb + 16];
        float4 v5 = *(const float4*)&row[kb + 20];
        float4 v6 = *(const float4*)&row[kb + 24];
        float4 v7 = *(const float4*)&row[kb + 28];
        uint4 o0, o1;
        o0.x = pack4(v0, scale); o0.y = pack4(v1, scale);
        o0.z = pack4(v2, scale); o0.w = pack4(v3, scale);
        o1.x = pack4(v4, scale); o1.y = pack4(v5, scale);
        o1.z = pack4(v6, scale); o1.w = pack4(v7, scale);
        *(uint4*)&outb[(long)k128 * 2048 + lane * 16] = o0;
        *(uint4*)&outb[(long)k128 * 2048 + 1024 + lane * 16] = o1;
    }
}

// ------- quantize + transpose weight (K,N) -> packed fp8 (N-major) -------
__global__ void quant_wt_kernel(const float* __restrict__ w,
                                unsigned char* __restrict__ qw,
                                const unsigned* __restrict__ amax) {
    __shared__ unsigned tile[128][17];    // [k][n-word], pad 17
    float scale = FP8_MAX / fmaxf(__uint_as_float(amax[1]), 1e-12f);
    int b = blockIdx.x;                   // 2048 = (K/128) * (N/64)
    int bk = b & (NK128 - 1), bn = b >> 5;
    int k0 = bk * 128, n0 = bn * 64;
    int t = threadIdx.x;
#pragma unroll
    for (int pass = 0; pass < 8; ++pass) {
        int idx = pass * 256 + t;         // 128 k x 16 words
        int k = idx >> 4, nw = idx & 15;
        float4 v = *(const float4*)&w[(long)(k0 + k) * N_DIM + n0 + nw * 4];
        tile[k][nw] = pack4(v, scale);
    }
    __syncthreads();
    int lane = t & 63;
    int n16l = t >> 6;                    // 0..3
    int nl = n16l * 16 + (lane & 15);
    int word = nl >> 2, sh = (nl & 3) * 8;
    int kb = (lane >> 4) * 32;
    long gn16 = (long)(n0 >> 4) + n16l;
    unsigned char* dst = qw + (gn16 * NK128 + bk) * 2048;
#pragma unroll
    for (int h = 0; h < 2; ++h) {
        uint4 o;
        unsigned* ow = (unsigned*)&o;
#pragma unroll
        for (int wd = 0; wd < 4; ++wd) {
            unsigned acc = 0;
#pragma unroll
            for (int j = 0; j < 4; ++j)
                acc |= ((tile[kb + h * 16 + wd * 4 + j][word] >> sh) & 0xffu) << (8 * j);
            ow[wd] = acc;
        }
        *(uint4*)&dst[h * 1024 + lane * 16] = o;
    }
}

// ---------------- MX-fp8 GEMM on packed operands ----------------
__device__ __forceinline__ void stage_tile(const unsigned char* __restrict__ Aseg,
                                           const unsigned char* __restrict__ Bseg,
                                           unsigned char* Al, unsigned char* Bl,
                                           int tid, int kt) {
#pragma unroll
    for (int r = 0; r < 4; ++r) {
        int c = r * 256 + tid;            // 0..1023
        int f = c >> 7;                   // row16-block 0..7
        int q = c & 127;                  // 16B chunk within 2048
        long goff = ((long)f * NK128 + kt) * 2048 + q * 16;
        __builtin_amdgcn_global_load_lds(
            (const __attribute__((address_space(1))) void*)(Aseg + goff),
            (__attribute__((address_space(3))) void*)(Al + c * 16), 16, 0, 0);
        __builtin_amdgcn_global_load_lds(
            (const __attribute__((address_space(1))) void*)(Bseg + goff),
            (__attribute__((address_space(3))) void*)(Bl + c * 16), 16, 0, 0);
    }
}

__global__ __launch_bounds__(256) void gemm_fp8_kernel(
    const unsigned char* __restrict__ qa, const unsigned char* __restrict__ qw,
    float* __restrict__ out, const unsigned* __restrict__ amax) {
    __shared__ unsigned char Alds[2][8 * 2048];  // 16KB x2
    __shared__ unsigned char Blds[2][8 * 2048];  // 16KB x2

    // XCD-bijective swizzle (nwg = 4096, divisible by 8)
    int b = blockIdx.x;
    int swz = (b & 7) * ((M_DIM / BM) * (N_DIM / BN) / 8) + (b >> 3);
    int bm = swz >> 5;          // N_DIM/BN = 32
    int bn = swz & 31;

    int tid = threadIdx.x;
    int lane = tid & 63;
    int w = tid >> 6;
    int wm = w >> 1, wn = w & 1;   // 2x2 wave grid, 64x64 out per wave

    f32x4 acc[4][4];
#pragma unroll
    for (int i = 0; i < 4; ++i)
#pragma unroll
        for (int j = 0; j < 4; ++j) acc[i][j] = (f32x4)0.f;

    const unsigned char* Aseg = qa + (long)(bm * 8) * NK128 * 2048;
    const unsigned char* Bseg = qw + (long)(bn * 8) * NK128 * 2048;

    stage_tile(Aseg, Bseg, &Alds[0][0], &Blds[0][0], tid, 0);
    __syncthreads();

    int abase = wm * 4 * 2048 + lane * 16;
    int bbase = wn * 4 * 2048 + lane * 16;

    int cur = 0;
    for (int kt = 0; kt < NKT; ++kt) {
        if (kt + 1 < NKT)
            stage_tile(Aseg, Bseg, &Alds[cur ^ 1][0], &Blds[cur ^ 1][0], tid, kt + 1);
        i32x8 af[4], bf[4];
#pragma unroll
        for (int i = 0; i < 4; ++i) {
            i32x4 lo = *(const i32x4*)&Alds[cur][abase + i * 2048];
            i32x4 hi = *(const i32x4*)&Alds[cur][abase + i * 2048 + 1024];
            af[i] = __builtin_shufflevector(lo, hi, 0, 1, 2, 3, 4, 5, 6, 7);
        }
#pragma unroll
        for (int j = 0; j < 4; ++j) {
            i32x4 lo = *(const i32x4*)&Blds[cur][bbase + j * 2048];
            i32x4 hi = *(const i32x4*)&Blds[cur][bbase + j * 2048 + 1024];
            bf[j] = __builtin_shufflevector(lo, hi, 0, 1, 2, 3, 4, 5, 6, 7);
        }
#pragma unroll
        for (int i = 0; i < 4; ++i)
#pragma unroll
            for (int j = 0; j < 4; ++j)
                acc[i][j] = __builtin_amdgcn_mfma_scale_f32_16x16x128_f8f6f4(
                    af[i], bf[j], acc[i][j], 0, 0,   // cbsz=FP8, blgp=FP8
                    0, 0x7f7f7f7f,                   // opsel_a, scale_a = 1.0
                    0, 0x7f7f7f7f);                  // opsel_b, scale_b = 1.0
        __syncthreads();   // drains vmcnt: next buffer staged; reads of cur done
        cur ^= 1;
    }

    // epilogue: dequant scale = (amax_x/448) * (amax_w/448)
    float ax = fmaxf(__uint_as_float(amax[0]), 1e-12f);
    float aw = fmaxf(__uint_as_float(amax[1]), 1e-12f);
    float s = ax * aw * (1.0f / (FP8_MAX * FP8_MAX));

    long m0 = (long)bm * BM;
    long n0 = (long)bn * BN;
    long crow0 = m0 + wm * 64 + ((lane >> 4) * 4);
    long ccol0 = n0 + wn * 64 + (lane & 15);
#pragma unroll
    for (int i = 0; i < 4; ++i)
#pragma unroll
        for (int j = 0; j < 4; ++j)
#pragma unroll
            for (int r = 0; r < 4; ++r)
                out[(crow0 + i * 16 + r) * N_DIM + ccol0 + j * 16] = acc[i][j][r] * s;
}

extern "C" void kernel_launch(void* const* d_in, const int* in_sizes, int n_in,
                              void* d_out, int out_size, void* d_ws, size_t ws_size,
                              hipStream_t stream) {
    const float* x = (const float*)d_in[0];       // (8,2048,4096) = (M,K)
    const float* wgt = (const float*)d_in[1];     // (K,N)
    float* out = (float*)d_out;

    // workspace layout
    unsigned* amax = (unsigned*)d_ws;                         // 2 words
    unsigned char* qa = (unsigned char*)d_ws + 256;           // M*K fp8 = 64MB packed
    unsigned char* qw = qa + (long)M_DIM * K_DIM;             // N*K fp8 = 16MB packed

    init_amax_kernel<<<1, 64, 0, stream>>>(amax);
    amax_kernel<<<2048, 256, 0, stream>>>(x, (long)M_DIM * K_DIM / 4, amax + 0);
    amax_kernel<<<1024, 256, 0, stream>>>(wgt, (long)K_DIM * N_DIM / 4, amax + 1);
    quant_x_kernel<<<M_DIM / 16, 256, 0, stream>>>(x, qa, amax);
    quant_wt_kernel<<<NK128 * (N_DIM / 64), 256, 0, stream>>>(wgt, qw, amax);

    dim3 grid((M_DIM / BM) * (N_DIM / BN));  // 4096
    gemm_fp8_kernel<<<grid, 256, 0, stream>>>(qa, qw, out, amax);
}

// Round 4
// 463.810 us; speedup vs baseline: 2.4231x; 1.4876x over previous
//
#include <hip/hip_runtime.h>
#include <hip/hip_bf16.h>

#define M_DIM 16384
#define N_DIM 4096
#define K_DIM 4096
#define FP8_MAX 448.0f

#define BM 256
#define BN 256
#define NK64 (K_DIM / 64)   // 64 k64-blocks = K-tiles
#define NKT NK64

typedef float f32x16 __attribute__((ext_vector_type(16)));
typedef int i32x4 __attribute__((ext_vector_type(4)));
typedef int i32x8 __attribute__((ext_vector_type(8)));

// Packed fp8 operand layout (A and B identical), matched to the
// mfma_scale_f32_32x32x64_f8f6f4 fragment: lane l holds
//   row = row32*32 + (l&31),  k = k64*64 + (l>>5)*32 + h*16 + j  (h=0,1; j=0..15)
// stored as [row32-block][k64-block][h][lane][16B]  (block = 2048 B).
// => GEMM LDS reads: ds_read_b128 @ base + lane*16 (conflict-free),
//    staging linear via global_load_lds w=16; quant kernels bake the order.
// All e8m0 scales = 127 (1.0) -> bit-identical to plain fp8 GEMM math.

// ---------------- init ----------------
__global__ void init_amax_kernel(unsigned* amax) {
    if (threadIdx.x < 2) amax[threadIdx.x] = 0u;
}

// ---------------- amax reduction ----------------
__global__ void amax_kernel(const float* __restrict__ p, long n4,
                            unsigned* __restrict__ out) {
    float m = 0.f;
    const float4* p4 = (const float4*)p;
    for (long i = (long)blockIdx.x * blockDim.x + threadIdx.x; i < n4;
         i += (long)gridDim.x * blockDim.x) {
        float4 v = p4[i];
        m = fmaxf(m, fmaxf(fmaxf(fabsf(v.x), fabsf(v.y)),
                           fmaxf(fabsf(v.z), fabsf(v.w))));
    }
#pragma unroll
    for (int off = 32; off > 0; off >>= 1)
        m = fmaxf(m, __shfl_down(m, off));
    __shared__ float smax[4];
    int lane = threadIdx.x & 63, wid = threadIdx.x >> 6;
    if (lane == 0) smax[wid] = m;
    __syncthreads();
    if (threadIdx.x == 0) {
        float bm = fmaxf(fmaxf(smax[0], smax[1]), fmaxf(smax[2], smax[3]));
        atomicMax(out, __float_as_uint(bm));  // positive floats: bit order == value order
    }
}

__device__ __forceinline__ unsigned pack4(float4 v, float s) {
    float a = fminf(fmaxf(v.x * s, -FP8_MAX), FP8_MAX);
    float b = fminf(fmaxf(v.y * s, -FP8_MAX), FP8_MAX);
    float c = fminf(fmaxf(v.z * s, -FP8_MAX), FP8_MAX);
    float d = fminf(fmaxf(v.w * s, -FP8_MAX), FP8_MAX);
    int p = 0;
    p = __builtin_amdgcn_cvt_pk_fp8_f32(a, b, p, false);
    p = __builtin_amdgcn_cvt_pk_fp8_f32(c, d, p, true);
    return (unsigned)p;
}

// ---------------- quantize x (M,K) fp32 -> packed fp8 ----------------
__global__ void quant_x_kernel(const float* __restrict__ x,
                               unsigned char* __restrict__ q,
                               const unsigned* __restrict__ amax) {
    float scale = FP8_MAX / fmaxf(__uint_as_float(amax[0]), 1e-12f);
    int m32 = blockIdx.x;                 // 0..511 (M/32)
    int t = threadIdx.x;
    int lane = t & 63;
    int g = t >> 6;                       // 0..3: k64 sub-block per iteration
    int m = m32 * 32 + (lane & 31);
    int kh = lane >> 5;                   // k-half of the 64-wide K block
    const float* rp = x + (long)m * K_DIM;
    unsigned char* ob = q + (long)m32 * NK64 * 2048;
#pragma unroll
    for (int it = 0; it < 16; ++it) {     // 64 k64-blocks, 4 per iter
        int k64 = it * 4 + g;
        int kb = k64 * 64 + kh * 32;
        float4 v0 = *(const float4*)&rp[kb];
        float4 v1 = *(const float4*)&rp[kb + 4];
        float4 v2 = *(const float4*)&rp[kb + 8];
        float4 v3 = *(const float4*)&rp[kb + 12];
        float4 v4 = *(const float4*)&rp[kb + 16];
        float4 v5 = *(const float4*)&rp[kb + 20];
        float4 v6 = *(const float4*)&rp[kb + 24];
        float4 v7 = *(const float4*)&rp[kb + 28];
        uint4 o0, o1;
        o0.x = pack4(v0, scale); o0.y = pack4(v1, scale);
        o0.z = pack4(v2, scale); o0.w = pack4(v3, scale);
        o1.x = pack4(v4, scale); o1.y = pack4(v5, scale);
        o1.z = pack4(v6, scale); o1.w = pack4(v7, scale);
        *(uint4*)&ob[(long)k64 * 2048 + lane * 16] = o0;          // h=0
        *(uint4*)&ob[(long)k64 * 2048 + 1024 + lane * 16] = o1;   // h=1
    }
}

// ------- quantize + transpose weight (K,N) -> packed fp8 (N-major) -------
__global__ void quant_wt_kernel(const float* __restrict__ w,
                                unsigned char* __restrict__ qw,
                                const unsigned* __restrict__ amax) {
    __shared__ unsigned tile[64][17];     // [k][n-word], pad 17
    float scale = FP8_MAX / fmaxf(__uint_as_float(amax[1]), 1e-12f);
    int b = blockIdx.x;                   // 4096 = (K/64) * (N/64)
    int bk = b & 63, bn = b >> 6;
    int k0 = bk * 64, n0 = bn * 64;
    int t = threadIdx.x;
#pragma unroll
    for (int pass = 0; pass < 4; ++pass) {
        int idx = pass * 256 + t;         // 64 k x 16 words
        int k = idx >> 4, nw = idx & 15;
        float4 v = *(const float4*)&w[(long)(k0 + k) * N_DIM + n0 + nw * 4];
        tile[k][nw] = pack4(v, scale);
    }
    __syncthreads();
    int lane = t & 63, g = t >> 6;
    int n32 = g >> 1, h = g & 1;          // 2 n32-blocks x 2 halves
    int nl = n32 * 32 + (lane & 31);
    int word = nl >> 2, sh = (nl & 3) * 8;
    int kb = (lane >> 5) * 32 + h * 16;
    uint4 o;
    unsigned* ow = (unsigned*)&o;
#pragma unroll
    for (int wd = 0; wd < 4; ++wd) {
        unsigned acc = 0;
#pragma unroll
        for (int j = 0; j < 4; ++j)
            acc |= ((tile[kb + wd * 4 + j][word] >> sh) & 0xffu) << (8 * j);
        ow[wd] = acc;
    }
    long gn32 = (long)(n0 >> 5) + n32;
    *(uint4*)&qw[(gn32 * NK64 + bk) * 2048 + h * 1024 + lane * 16] = o;
}

// ---------------- MX-fp8 GEMM, 256x256 tile, counted-vmcnt pipeline ----------------
__device__ __forceinline__ void stage_q(const unsigned char* __restrict__ Aseg,
                                        const unsigned char* __restrict__ Bseg,
                                        unsigned char* stbuf, int tid, int kt, int r) {
    int c = r * 512 + tid;                // 0..2047: 1024 A chunks then 1024 B
    int f = (c >> 7) & 7;                 // row32-block 0..7
    int q = c & 127;
    const unsigned char* src =
        ((c < 1024) ? Aseg : Bseg) + ((long)f * NK64 + kt) * 2048 + q * 16;
    __builtin_amdgcn_global_load_lds(
        (const __attribute__((address_space(1))) void*)src,
        (__attribute__((address_space(3))) void*)(stbuf + c * 16), 16, 0, 0);
}

__device__ __forceinline__ i32x8 comb(i32x4 lo, i32x4 hi) {
    return __builtin_shufflevector(lo, hi, 0, 1, 2, 3, 4, 5, 6, 7);
}

template <int VW, bool STG>
__device__ __forceinline__ void tile_step(unsigned char* sbase,
                                          const unsigned char* __restrict__ Aseg,
                                          const unsigned char* __restrict__ Bseg,
                                          int kt, int tid, int lane, int wm, int wn,
                                          f32x16 (&acc)[4][2]) {
    unsigned char* buf = sbase + (size_t)(kt & 3) * 32768;
    unsigned char* stbuf = sbase + (size_t)((kt + 3) & 3) * 32768;
    const unsigned char* Al = buf + wm * 4 * 2048;
    const unsigned char* Bl = buf + 16384 + wn * 2 * 2048;

    // ---- phase 0: A frags (reused both phases) + B0 ; stage r=0,1 ----
    i32x4 a[4][2], b0lo, b0hi;
#pragma unroll
    for (int i = 0; i < 4; ++i) {
        a[i][0] = *(const i32x4*)(Al + i * 2048 + lane * 16);
        a[i][1] = *(const i32x4*)(Al + i * 2048 + 1024 + lane * 16);
    }
    b0lo = *(const i32x4*)(Bl + lane * 16);
    b0hi = *(const i32x4*)(Bl + 1024 + lane * 16);
    if (STG) {
        stage_q(Aseg, Bseg, stbuf, tid, kt + 3, 0);
        stage_q(Aseg, Bseg, stbuf, tid, kt + 3, 1);
    }
    __builtin_amdgcn_s_barrier();
    asm volatile("s_waitcnt lgkmcnt(0)" ::: "memory");
    __builtin_amdgcn_sched_barrier(0);
    __builtin_amdgcn_s_setprio(1);
    {
        i32x8 bf = comb(b0lo, b0hi);
#pragma unroll
        for (int i = 0; i < 4; ++i)
            acc[i][0] = __builtin_amdgcn_mfma_scale_f32_32x32x64_f8f6f4(
                comb(a[i][0], a[i][1]), bf, acc[i][0], 0, 0,
                0, 0x7f7f7f7f, 0, 0x7f7f7f7f);
    }
    __builtin_amdgcn_s_setprio(0);
    __builtin_amdgcn_s_barrier();

    // ---- phase 1: B1 ; stage r=2,3 ----
    i32x4 b1lo = *(const i32x4*)(Bl + 2048 + lane * 16);
    i32x4 b1hi = *(const i32x4*)(Bl + 2048 + 1024 + lane * 16);
    if (STG) {
        stage_q(Aseg, Bseg, stbuf, tid, kt + 3, 2);
        stage_q(Aseg, Bseg, stbuf, tid, kt + 3, 3);
    }
    __builtin_amdgcn_s_barrier();
    asm volatile("s_waitcnt lgkmcnt(0)" ::: "memory");
    __builtin_amdgcn_sched_barrier(0);
    __builtin_amdgcn_s_setprio(1);
    {
        i32x8 bf = comb(b1lo, b1hi);
#pragma unroll
        for (int i = 0; i < 4; ++i)
            acc[i][1] = __builtin_amdgcn_mfma_scale_f32_32x32x64_f8f6f4(
                comb(a[i][0], a[i][1]), bf, acc[i][1], 0, 0,
                0, 0x7f7f7f7f, 0, 0x7f7f7f7f);
    }
    __builtin_amdgcn_s_setprio(0);
    // counted drain: tiles kt+1..kt+3 in flight (4 loads each); wait oldest
    if constexpr (VW == 8) asm volatile("s_waitcnt vmcnt(8)" ::: "memory");
    else if constexpr (VW == 4) asm volatile("s_waitcnt vmcnt(4)" ::: "memory");
    else if constexpr (VW == 0) asm volatile("s_waitcnt vmcnt(0)" ::: "memory");
    if constexpr (VW >= 0) __builtin_amdgcn_s_barrier();
}

__global__ __launch_bounds__(512, 2) void gemm_fp8_kernel(
    const unsigned char* __restrict__ qa, const unsigned char* __restrict__ qw,
    float* __restrict__ out, const unsigned* __restrict__ amax) {
    __shared__ unsigned char lds[4][32768];   // 128 KB: 4 buffers (A 16K + B 16K)

    // XCD-bijective swizzle (nwg = 1024, divisible by 8)
    int b = blockIdx.x;
    int swz = (b & 7) * 128 + (b >> 3);
    int bm = swz >> 4;            // M/BM = 64 ; N/BN = 16
    int bn = swz & 15;

    int tid = threadIdx.x;
    int lane = tid & 63;
    int w = tid >> 6;
    int wm = w >> 2, wn = w & 3;  // 2x4 wave grid, wave tile 128x64

    f32x16 acc[4][2];
#pragma unroll
    for (int i = 0; i < 4; ++i)
#pragma unroll
        for (int j = 0; j < 2; ++j) acc[i][j] = (f32x16)0.f;

    const unsigned char* Aseg = qa + (long)(bm * 8) * NK64 * 2048;
    const unsigned char* Bseg = qw + (long)(bn * 8) * NK64 * 2048;
    unsigned char* sbase = &lds[0][0];

    // prologue: stage tiles 0,1,2 (depth-3)
#pragma unroll
    for (int pt = 0; pt < 3; ++pt)
#pragma unroll
        for (int r = 0; r < 4; ++r)
            stage_q(Aseg, Bseg, sbase + (size_t)pt * 32768, tid, pt, r);
    asm volatile("s_waitcnt vmcnt(8)" ::: "memory");  // tile 0 resident
    __builtin_amdgcn_s_barrier();

#pragma unroll 1
    for (int kt = 0; kt < NKT - 3; ++kt)
        tile_step<8, true>(sbase, Aseg, Bseg, kt, tid, lane, wm, wn, acc);
    tile_step<4, false>(sbase, Aseg, Bseg, NKT - 3, tid, lane, wm, wn, acc);
    tile_step<0, false>(sbase, Aseg, Bseg, NKT - 2, tid, lane, wm, wn, acc);
    tile_step<-1, false>(sbase, Aseg, Bseg, NKT - 1, tid, lane, wm, wn, acc);

    // epilogue: dequant scale = (amax_x/448) * (amax_w/448)
    float ax = fmaxf(__uint_as_float(amax[0]), 1e-12f);
    float aw = fmaxf(__uint_as_float(amax[1]), 1e-12f);
    float s = ax * aw * (1.0f / (FP8_MAX * FP8_MAX));

    long m0 = (long)bm * BM + wm * 128;
    long n0 = (long)bn * BN + wn * 64;
    int col = lane & 31;
    int rbase = 4 * (lane >> 5);
#pragma unroll
    for (int i = 0; i < 4; ++i)
#pragma unroll
        for (int j = 0; j < 2; ++j)
#pragma unroll
            for (int reg = 0; reg < 16; ++reg) {
                int row = (reg & 3) + 8 * (reg >> 2) + rbase;
                out[(m0 + i * 32 + row) * N_DIM + n0 + j * 32 + col] =
                    acc[i][j][reg] * s;
            }
}

extern "C" void kernel_launch(void* const* d_in, const int* in_sizes, int n_in,
                              void* d_out, int out_size, void* d_ws, size_t ws_size,
                              hipStream_t stream) {
    const float* x = (const float*)d_in[0];       // (8,2048,4096) = (M,K)
    const float* wgt = (const float*)d_in[1];     // (K,N)
    float* out = (float*)d_out;

    // workspace layout
    unsigned* amax = (unsigned*)d_ws;                         // 2 words
    unsigned char* qa = (unsigned char*)d_ws + 256;           // M*K fp8 = 64MB packed
    unsigned char* qw = qa + (long)M_DIM * K_DIM;             // N*K fp8 = 16MB packed

    init_amax_kernel<<<1, 64, 0, stream>>>(amax);
    amax_kernel<<<2048, 256, 0, stream>>>(x, (long)M_DIM * K_DIM / 4, amax + 0);
    amax_kernel<<<1024, 256, 0, stream>>>(wgt, (long)K_DIM * N_DIM / 4, amax + 1);
    quant_x_kernel<<<M_DIM / 32, 256, 0, stream>>>(x, qa, amax);
    quant_wt_kernel<<<(K_DIM / 64) * (N_DIM / 64), 256, 0, stream>>>(wgt, qw, amax);

    dim3 grid((M_DIM / BM) * (N_DIM / BN));  // 1024
    gemm_fp8_kernel<<<grid, 512, 0, stream>>>(qa, qw, out, amax);
}

// Round 6
// 460.495 us; speedup vs baseline: 2.4406x; 1.0072x over previous
//
#include <hip/hip_runtime.h>
#include <hip/hip_bf16.h>

#define M_DIM 16384
#define N_DIM 4096
#define K_DIM 4096
#define FP8_MAX 448.0f

#define BM 256
#define BN 256
#define NK64 (K_DIM / 64)   // 64 k64-blocks = K-tiles
#define NKT NK64

typedef float f32x16 __attribute__((ext_vector_type(16)));
typedef int i32x4 __attribute__((ext_vector_type(4)));
typedef int i32x8 __attribute__((ext_vector_type(8)));

// Packed fp8 operand layout (A and B identical), matched to the
// mfma_scale_f32_32x32x64_f8f6f4 fragment: lane l holds
//   row = row32*32 + (l&31),  k = k64*64 + (l>>5)*32 + h*16 + j  (h=0,1; j=0..15)
// stored as [row32-block][k64-block][h][lane][16B]  (block = 2048 B).
// GEMM: reg-double-buffered pipeline. Sync per step (the R4 bug fix):
//   vmcnt(4)+lgkmcnt(0)  -> own loads for tile kt+1 done, own ds_reads done
//   s_barrier            -> ALL waves' staging for tile kt+1 visible
//   ds_read kt+1 frags ; stage kt+3 ; then MFMA cluster on kt (regs)
// scales = 1.0 e8m0 -> bit-identical to plain fp8 GEMM math.

// ---------------- init ----------------
__global__ void init_amax_kernel(unsigned* amax) {
    if (threadIdx.x < 2) amax[threadIdx.x] = 0u;
}

// ---------------- amax reduction ----------------
__global__ void amax_kernel(const float* __restrict__ p, long n4,
                            unsigned* __restrict__ out) {
    float m = 0.f;
    const float4* p4 = (const float4*)p;
    for (long i = (long)blockIdx.x * blockDim.x + threadIdx.x; i < n4;
         i += (long)gridDim.x * blockDim.x) {
        float4 v = p4[i];
        m = fmaxf(m, fmaxf(fmaxf(fabsf(v.x), fabsf(v.y)),
                           fmaxf(fabsf(v.z), fabsf(v.w))));
    }
#pragma unroll
    for (int off = 32; off > 0; off >>= 1)
        m = fmaxf(m, __shfl_down(m, off));
    __shared__ float smax[4];
    int lane = threadIdx.x & 63, wid = threadIdx.x >> 6;
    if (lane == 0) smax[wid] = m;
    __syncthreads();
    if (threadIdx.x == 0) {
        float bm = fmaxf(fmaxf(smax[0], smax[1]), fmaxf(smax[2], smax[3]));
        atomicMax(out, __float_as_uint(bm));  // positive floats: bit order == value order
    }
}

__device__ __forceinline__ unsigned pack4(float4 v, float s) {
    float a = fminf(fmaxf(v.x * s, -FP8_MAX), FP8_MAX);
    float b = fminf(fmaxf(v.y * s, -FP8_MAX), FP8_MAX);
    float c = fminf(fmaxf(v.z * s, -FP8_MAX), FP8_MAX);
    float d = fminf(fmaxf(v.w * s, -FP8_MAX), FP8_MAX);
    int p = 0;
    p = __builtin_amdgcn_cvt_pk_fp8_f32(a, b, p, false);
    p = __builtin_amdgcn_cvt_pk_fp8_f32(c, d, p, true);
    return (unsigned)p;
}

// ---------------- quantize x (M,K) fp32 -> packed fp8 ----------------
__global__ void quant_x_kernel(const float* __restrict__ x,
                               unsigned char* __restrict__ q,
                               const unsigned* __restrict__ amax) {
    float scale = FP8_MAX / fmaxf(__uint_as_float(amax[0]), 1e-12f);
    int m32 = blockIdx.x;                 // 0..511 (M/32)
    int t = threadIdx.x;
    int lane = t & 63;
    int g = t >> 6;                       // 0..3: k64 sub-block per iteration
    int m = m32 * 32 + (lane & 31);
    int kh = lane >> 5;                   // k-half of the 64-wide K block
    const float* rp = x + (long)m * K_DIM;
    unsigned char* ob = q + (long)m32 * NK64 * 2048;
#pragma unroll
    for (int it = 0; it < 16; ++it) {     // 64 k64-blocks, 4 per iter
        int k64 = it * 4 + g;
        int kb = k64 * 64 + kh * 32;
        float4 v0 = *(const float4*)&rp[kb];
        float4 v1 = *(const float4*)&rp[kb + 4];
        float4 v2 = *(const float4*)&rp[kb + 8];
        float4 v3 = *(const float4*)&rp[kb + 12];
        float4 v4 = *(const float4*)&rp[kb + 16];
        float4 v5 = *(const float4*)&rp[kb + 20];
        float4 v6 = *(const float4*)&rp[kb + 24];
        float4 v7 = *(const float4*)&rp[kb + 28];
        uint4 o0, o1;
        o0.x = pack4(v0, scale); o0.y = pack4(v1, scale);
        o0.z = pack4(v2, scale); o0.w = pack4(v3, scale);
        o1.x = pack4(v4, scale); o1.y = pack4(v5, scale);
        o1.z = pack4(v6, scale); o1.w = pack4(v7, scale);
        *(uint4*)&ob[(long)k64 * 2048 + lane * 16] = o0;          // h=0
        *(uint4*)&ob[(long)k64 * 2048 + 1024 + lane * 16] = o1;   // h=1
    }
}

// ------- quantize + transpose weight (K,N) -> packed fp8 (N-major) -------
__global__ void quant_wt_kernel(const float* __restrict__ w,
                                unsigned char* __restrict__ qw,
                                const unsigned* __restrict__ amax) {
    __shared__ unsigned tile[64][17];     // [k][n-word], pad 17
    float scale = FP8_MAX / fmaxf(__uint_as_float(amax[1]), 1e-12f);
    int b = blockIdx.x;                   // 4096 = (K/64) * (N/64)
    int bk = b & 63, bn = b >> 6;
    int k0 = bk * 64, n0 = bn * 64;
    int t = threadIdx.x;
#pragma unroll
    for (int pass = 0; pass < 4; ++pass) {
        int idx = pass * 256 + t;         // 64 k x 16 words
        int k = idx >> 4, nw = idx & 15;
        float4 v = *(const float4*)&w[(long)(k0 + k) * N_DIM + n0 + nw * 4];
        tile[k][nw] = pack4(v, scale);
    }
    __syncthreads();
    int lane = t & 63, g = t >> 6;
    int n32 = g >> 1, h = g & 1;          // 2 n32-blocks x 2 halves
    int nl = n32 * 32 + (lane & 31);
    int word = nl >> 2, sh = (nl & 3) * 8;
    int kb = (lane >> 5) * 32 + h * 16;
    uint4 o;
    unsigned* ow = (unsigned*)&o;
#pragma unroll
    for (int wd = 0; wd < 4; ++wd) {
        unsigned acc = 0;
#pragma unroll
        for (int j = 0; j < 4; ++j)
            acc |= ((tile[kb + wd * 4 + j][word] >> sh) & 0xffu) << (8 * j);
        ow[wd] = acc;
    }
    long gn32 = (long)(n0 >> 5) + n32;
    *(uint4*)&qw[(gn32 * NK64 + bk) * 2048 + h * 1024 + lane * 16] = o;
}

// ---------------- MX-fp8 GEMM, reg-double-buffered pipeline ----------------
__device__ __forceinline__ void stage_q(const unsigned char* __restrict__ Aseg,
                                        const unsigned char* __restrict__ Bseg,
                                        unsigned char* stbuf, int tid, int kt, int r) {
    int c = r * 512 + tid;                // 0..2047: 1024 A chunks then 1024 B
    int f = (c >> 7) & 7;                 // row32-block 0..7
    int q = c & 127;
    const unsigned char* src =
        ((c < 1024) ? Aseg : Bseg) + ((long)f * NK64 + kt) * 2048 + q * 16;
    __builtin_amdgcn_global_load_lds(
        (const __attribute__((address_space(1))) void*)src,
        (__attribute__((address_space(3))) void*)(stbuf + c * 16), 16, 0, 0);
}

__device__ __forceinline__ i32x8 comb(i32x4 lo, i32x4 hi) {
    return __builtin_shufflevector(lo, hi, 0, 1, 2, 3, 4, 5, 6, 7);
}

// One K-tile step. On entry: frags for tile kt live in (ca, cb).
// Gate+barrier, then read tile kt+1 frags into (na, nb) and stage tile kt+3,
// then the MFMA cluster on (ca, cb) — loads in flight under the MFMAs.
template <int VW, bool STG, bool NEXT>
__device__ __forceinline__ void tile_step(
    unsigned char* sbase, const unsigned char* __restrict__ Aseg,
    const unsigned char* __restrict__ Bseg, int kt, int tid, int lane,
    int wm, int wn, i32x4 (&ca)[4][2], i32x4 (&cb)[2][2],
    i32x4 (&na)[4][2], i32x4 (&nb)[2][2], f32x16 (&acc)[4][2]) {
    // gate: own staging loads for tile kt+1 landed AND own ds_reads drained;
    // then barrier -> ALL waves' staging for tile kt+1 visible (cross-wave).
    if constexpr (VW == 4)
        asm volatile("s_waitcnt vmcnt(4) lgkmcnt(0)" ::: "memory");
    else if constexpr (VW == 0)
        asm volatile("s_waitcnt vmcnt(0) lgkmcnt(0)" ::: "memory");
    if constexpr (VW >= 0) {
        __builtin_amdgcn_sched_barrier(0);
        __builtin_amdgcn_s_barrier();
        __builtin_amdgcn_sched_barrier(0);
    }

    if constexpr (NEXT) {
        const unsigned char* nbuf = sbase + (size_t)((kt + 1) & 3) * 32768;
        const unsigned char* nAl = nbuf + wm * 4 * 2048;
        const unsigned char* nBl = nbuf + 16384 + wn * 2 * 2048;
#pragma unroll
        for (int i = 0; i < 4; ++i) {
            na[i][0] = *(const i32x4*)(nAl + i * 2048 + lane * 16);
            na[i][1] = *(const i32x4*)(nAl + i * 2048 + 1024 + lane * 16);
        }
#pragma unroll
        for (int j = 0; j < 2; ++j) {
            nb[j][0] = *(const i32x4*)(nBl + j * 2048 + lane * 16);
            nb[j][1] = *(const i32x4*)(nBl + j * 2048 + 1024 + lane * 16);
        }
    }
    if constexpr (STG) {
        unsigned char* stbuf = sbase + (size_t)((kt + 3) & 3) * 32768;
        stage_q(Aseg, Bseg, stbuf, tid, kt + 3, 0);
        stage_q(Aseg, Bseg, stbuf, tid, kt + 3, 1);
        stage_q(Aseg, Bseg, stbuf, tid, kt + 3, 2);
        stage_q(Aseg, Bseg, stbuf, tid, kt + 3, 3);
    }
    // pin: MFMA cluster must not hoist above the read/stage issues
    __builtin_amdgcn_sched_barrier(0);
    __builtin_amdgcn_s_setprio(1);
#pragma unroll
    for (int i = 0; i < 4; ++i)
        acc[i][0] = __builtin_amdgcn_mfma_scale_f32_32x32x64_f8f6f4(
            comb(ca[i][0], ca[i][1]), comb(cb[0][0], cb[0][1]), acc[i][0],
            0, 0, 0, 0x7f7f7f7f, 0, 0x7f7f7f7f);
#pragma unroll
    for (int i = 0; i < 4; ++i)
        acc[i][1] = __builtin_amdgcn_mfma_scale_f32_32x32x64_f8f6f4(
            comb(ca[i][0], ca[i][1]), comb(cb[1][0], cb[1][1]), acc[i][1],
            0, 0, 0, 0x7f7f7f7f, 0, 0x7f7f7f7f);
    __builtin_amdgcn_s_setprio(0);
}

__global__ __launch_bounds__(512, 2) void gemm_fp8_kernel(
    const unsigned char* __restrict__ qa, const unsigned char* __restrict__ qw,
    float* __restrict__ out, const unsigned* __restrict__ amax) {
    __shared__ unsigned char lds[4][32768];   // 128 KB: 4 buffers (A 16K + B 16K)

    // XCD-bijective swizzle (nwg = 1024, divisible by 8)
    int b = blockIdx.x;
    int swz = (b & 7) * 128 + (b >> 3);
    int bm = swz >> 4;            // M/BM = 64 ; N/BN = 16
    int bn = swz & 15;

    int tid = threadIdx.x;
    int lane = tid & 63;
    int w = tid >> 6;
    int wm = w >> 2, wn = w & 3;  // 2x4 wave grid, wave tile 128x64

    f32x16 acc[4][2];
#pragma unroll
    for (int i = 0; i < 4; ++i)
#pragma unroll
        for (int j = 0; j < 2; ++j) acc[i][j] = (f32x16)0.f;

    const unsigned char* Aseg = qa + (long)(bm * 8) * NK64 * 2048;
    const unsigned char* Bseg = qw + (long)(bn * 8) * NK64 * 2048;
    unsigned char* sbase = &lds[0][0];

    // prologue: stage tiles 0,1,2 (depth-3)
#pragma unroll
    for (int pt = 0; pt < 3; ++pt)
#pragma unroll
        for (int r = 0; r < 4; ++r)
            stage_q(Aseg, Bseg, sbase + (size_t)pt * 32768, tid, pt, r);
    asm volatile("s_waitcnt vmcnt(8)" ::: "memory");  // tile 0 resident (own)
    __builtin_amdgcn_s_barrier();                      // ..for all waves

    i32x4 A0[4][2], B0[2][2], A1[4][2], B1[2][2];
    {   // read tile-0 fragments
        const unsigned char* Al = sbase + wm * 4 * 2048;
        const unsigned char* Bl = sbase + 16384 + wn * 2 * 2048;
#pragma unroll
        for (int i = 0; i < 4; ++i) {
            A0[i][0] = *(const i32x4*)(Al + i * 2048 + lane * 16);
            A0[i][1] = *(const i32x4*)(Al + i * 2048 + 1024 + lane * 16);
        }
#pragma unroll
        for (int j = 0; j < 2; ++j) {
            B0[j][0] = *(const i32x4*)(Bl + j * 2048 + lane * 16);
            B0[j][1] = *(const i32x4*)(Bl + j * 2048 + 1024 + lane * 16);
        }
    }

#pragma unroll 1
    for (int kt = 0; kt < 60; kt += 2) {
        tile_step<4, true, true>(sbase, Aseg, Bseg, kt, tid, lane, wm, wn,
                                 A0, B0, A1, B1, acc);
        tile_step<4, true, true>(sbase, Aseg, Bseg, kt + 1, tid, lane, wm, wn,
                                 A1, B1, A0, B0, acc);
    }
    tile_step<4, true, true>(sbase, Aseg, Bseg, 60, tid, lane, wm, wn,
                             A0, B0, A1, B1, acc);
    tile_step<4, false, true>(sbase, Aseg, Bseg, 61, tid, lane, wm, wn,
                              A1, B1, A0, B0, acc);
    tile_step<0, false, true>(sbase, Aseg, Bseg, 62, tid, lane, wm, wn,
                              A0, B0, A1, B1, acc);
    tile_step<-1, false, false>(sbase, Aseg, Bseg, 63, tid, lane, wm, wn,
                                A1, B1, A0, B0, acc);

    // epilogue: dequant scale = (amax_x/448) * (amax_w/448)
    float ax = fmaxf(__uint_as_float(amax[0]), 1e-12f);
    float aw = fmaxf(__uint_as_float(amax[1]), 1e-12f);
    float s = ax * aw * (1.0f / (FP8_MAX * FP8_MAX));

    long m0 = (long)bm * BM + wm * 128;
    long n0 = (long)bn * BN + wn * 64;
    int col = lane & 31;
    int rbase = 4 * (lane >> 5);
#pragma unroll
    for (int i = 0; i < 4; ++i)
#pragma unroll
        for (int j = 0; j < 2; ++j)
#pragma unroll
            for (int reg = 0; reg < 16; ++reg) {
                int row = (reg & 3) + 8 * (reg >> 2) + rbase;
                out[(m0 + i * 32 + row) * N_DIM + n0 + j * 32 + col] =
                    acc[i][j][reg] * s;
            }
}

extern "C" void kernel_launch(void* const* d_in, const int* in_sizes, int n_in,
                              void* d_out, int out_size, void* d_ws, size_t ws_size,
                              hipStream_t stream) {
    const float* x = (const float*)d_in[0];       // (8,2048,4096) = (M,K)
    const float* wgt = (const float*)d_in[1];     // (K,N)
    float* out = (float*)d_out;

    // workspace layout
    unsigned* amax = (unsigned*)d_ws;                         // 2 words
    unsigned char* qa = (unsigned char*)d_ws + 256;           // M*K fp8 = 64MB packed
    unsigned char* qw = qa + (long)M_DIM * K_DIM;             // N*K fp8 = 16MB packed

    init_amax_kernel<<<1, 64, 0, stream>>>(amax);
    amax_kernel<<<2048, 256, 0, stream>>>(x, (long)M_DIM * K_DIM / 4, amax + 0);
    amax_kernel<<<1024, 256, 0, stream>>>(wgt, (long)K_DIM * N_DIM / 4, amax + 1);
    quant_x_kernel<<<M_DIM / 32, 256, 0, stream>>>(x, qa, amax);
    quant_wt_kernel<<<(K_DIM / 64) * (N_DIM / 64), 256, 0, stream>>>(wgt, qw, amax);

    dim3 grid((M_DIM / BM) * (N_DIM / BN));  // 1024
    gemm_fp8_kernel<<<grid, 512, 0, stream>>>(qa, qw, out, amax);
}